// Round 22
// baseline (699.600 us; speedup 1.0000x reference)
//
#include <hip/hip_runtime.h>

// SNN: conv2d(3x3, same, no bias, Cin=Cout=64) + LIF scan (tau=2, v_th=1, hard reset)
// Numerics contract (R13, PASS R14/R15/R20/R21):
//   conv: f32, SINGLE FMA chain per output in flat (ci, ky, kx) order g=ci*9+k
//   scan: float64, v' = v + (z - v)*0.5, spike = v' >= 1.0, hard reset to 0.
// R22: remove the champion's only defect (25-reg spill, +240MB scratch traffic)
// by replacing the r[25] register prefetch with global_load_lds async staging:
//   - linear LDS tile [6400] (q = ci*100+hh*10+wl), dest = wave-uniform base +
//     lane*4 (the contiguous pattern global_load_lds requires, m104)
//   - per-lane global source; halo/OOB lanes read a zeroed 1KB pool in d_ws
//     (values bit-identical: 0.0f)
//   - double-buffered (2 x 25.6KB); __syncthreads()'s implicit vmcnt(0) drain
//     is the ready barrier; t+1's loads overlap t's conv.
// Compile mode pinned to the empirically-fast (256,4) regime.

#define T_STEPS 8
#define BATCH   16
#define CIN     64
#define COUT    64
#define IMH     64
#define IMW     64
#define HW      (IMH * IMW)
#define X_ELEMS (T_STEPS * BATCH * CIN * HW)   // 33,554,432
#define W_ELEMS (COUT * CIN * 9)               // 36,864
#define W_BYTES (W_ELEMS * 4)                  // 147,456 (256-aligned)

typedef const __attribute__((address_space(1))) float gfloat;
typedef __attribute__((address_space(3))) float lfloat;

// [co][g] -> [g][co]: per (ci,k) step, a wave's 16 weights are one contiguous
// 64B block (float4-loadable, L2-hot).
__global__ void transpose_weights(const float* __restrict__ wf, float* __restrict__ wt) {
    int i = blockIdx.x * 256 + threadIdx.x;     // i = co*576 + g
    if (i < W_ELEMS) {
        int co = i / 576;
        int g  = i - co * 576;
        wt[g * 64 + co] = wf[i];
    }
}

// Issue 25 async global->LDS copies for this thread's slots q = tid + j*256.
// Wave w, iter j covers LDS slots [j*256 + w*64, +64) contiguously: dest =
// uniform base + lane*4 exactly matches global_load_lds's write pattern.
__device__ __forceinline__ void stage_async(const float* __restrict__ xim,
                                            float* lds_lin,
                                            const float* __restrict__ zp,
                                            int h0, int w0, int tid) {
#pragma unroll
    for (int j = 0; j < 25; ++j) {
        int q   = tid + j * 256;             // 0..6399
        int ci  = q / 100;
        int rem = q - ci * 100;
        int hh  = rem / 10;
        int wl  = rem - hh * 10;
        int gh  = h0 - 1 + hh;
        int gw  = w0 - 1 + wl;
        const float* src = ((unsigned)gh < IMH && (unsigned)gw < IMW)
                         ? (xim + ci * HW + gh * IMW + gw) : zp;
        __builtin_amdgcn_global_load_lds((gfloat*)src, (lfloat*)(lds_lin + q), 4, 0, 0);
    }
}

__global__ __launch_bounds__(256, 4)
void snn_conv_lif_f0(const float* __restrict__ x, const float* __restrict__ wt,
                     const float* __restrict__ zp, float* __restrict__ out) {
    __shared__ float xt[2][6400];            // linear, double-buffered: 51.2 KB

    const int tid  = threadIdx.x;
    const int lane = tid & 63;
    const int wid  = __builtin_amdgcn_readfirstlane(tid >> 6);

    const int b    = blockIdx.x >> 6;        // 0..15
    const int tile = blockIdx.x & 63;        // 64 tiles of 8x8
    const int h0   = (tile >> 3) << 3;
    const int w0   = (tile & 7) << 3;
    const int ph   = lane >> 3;
    const int pw   = lane & 7;
    const int cobase = wid << 4;             // 16 c_out per wave
    const int oh = h0 + ph, ow = w0 + pw;

    double v[16];                            // f64 LIF state
#pragma unroll
    for (int i = 0; i < 16; ++i) v[i] = 0.0;

    // prologue: issue t=0 staging into buf 0
    stage_async(x + (size_t)b * CIN * HW, xt[0], zp, h0, w0, tid);
    int cur = 0;

    for (int t = 0; t < T_STEPS; ++t) {
        // implicit s_waitcnt vmcnt(0) before s_barrier: buf[cur] ready, and all
        // waves are done reading buf[cur^1] (t-1's conv finished before here).
        __syncthreads();

        // ---- issue t+1 staging into the other buffer; overlaps conv below ----
        if (t + 1 < T_STEPS)
            stage_async(x + (size_t)((t + 1) * BATCH + b) * CIN * HW,
                        xt[cur ^ 1], zp, h0, w0, tid);

        // ---- conv: per c_out, ONE sequential FMA chain over g = ci*9+k ----
        const float* xb = xt[cur];
        float z[16];
#pragma unroll
        for (int i = 0; i < 16; ++i) z[i] = 0.0f;

        for (int ci = 0; ci < CIN; ++ci) {
            float nb[9];
#pragma unroll
            for (int dy = 0; dy < 3; ++dy)
#pragma unroll
                for (int dx = 0; dx < 3; ++dx)
                    nb[dy * 3 + dx] = xb[ci * 100 + (ph + dy) * 10 + (pw + dx)];

#pragma unroll
            for (int k = 0; k < 9; ++k) {
                float xv = nb[k];
                const float4* w4 = (const float4*)(wt + (ci * 9 + k) * 64 + cobase);
                float4 wa = w4[0], wb = w4[1], wc = w4[2], wd = w4[3];
                z[0]  = __builtin_fmaf(wa.x, xv, z[0]);
                z[1]  = __builtin_fmaf(wa.y, xv, z[1]);
                z[2]  = __builtin_fmaf(wa.z, xv, z[2]);
                z[3]  = __builtin_fmaf(wa.w, xv, z[3]);
                z[4]  = __builtin_fmaf(wb.x, xv, z[4]);
                z[5]  = __builtin_fmaf(wb.y, xv, z[5]);
                z[6]  = __builtin_fmaf(wb.z, xv, z[6]);
                z[7]  = __builtin_fmaf(wb.w, xv, z[7]);
                z[8]  = __builtin_fmaf(wc.x, xv, z[8]);
                z[9]  = __builtin_fmaf(wc.y, xv, z[9]);
                z[10] = __builtin_fmaf(wc.z, xv, z[10]);
                z[11] = __builtin_fmaf(wc.w, xv, z[11]);
                z[12] = __builtin_fmaf(wd.x, xv, z[12]);
                z[13] = __builtin_fmaf(wd.y, xv, z[13]);
                z[14] = __builtin_fmaf(wd.z, xv, z[14]);
                z[15] = __builtin_fmaf(wd.w, xv, z[15]);
            }
        }

        // ---- f64 LIF scan ----
        size_t obase = ((size_t)(t * BATCH + b) * COUT + cobase) * HW
                     + (size_t)oh * IMW + ow;
#pragma unroll
        for (int i = 0; i < 16; ++i) {
            double d  = (double)z[i] - v[i];
            double nv = v[i] + d * 0.5;
            bool  sp  = (nv >= 1.0);
            out[obase + (size_t)i * HW] = sp ? 1.0f : 0.0f;
            v[i] = sp ? 0.0 : nv;
        }
        cur ^= 1;
    }
}

// Fallback without workspace: identical numerics (R14-style).
__global__ __launch_bounds__(256)
void snn_conv_lif_f0_direct(const float* __restrict__ x, const float* __restrict__ cw,
                            float* __restrict__ out) {
    __shared__ float xt[CIN][10][12];

    const int tid  = threadIdx.x;
    const int lane = tid & 63;
    const int wid  = __builtin_amdgcn_readfirstlane(tid >> 6);
    const int b    = blockIdx.x >> 6;
    const int tile = blockIdx.x & 63;
    const int h0   = (tile >> 3) << 3;
    const int w0   = (tile & 7) << 3;
    const int ph   = lane >> 3, pw = lane & 7;
    const int cobase = wid << 4;
    const int oh = h0 + ph, ow = w0 + pw;

    double v[16];
#pragma unroll
    for (int i = 0; i < 16; ++i) v[i] = 0.0;

    for (int t = 0; t < T_STEPS; ++t) {
        __syncthreads();
        const float* xim = x + (size_t)(t * BATCH + b) * CIN * HW;
#pragma unroll
        for (int j = 0; j < 25; ++j) {
            int q   = tid + j * 256;
            int ci  = q / 100;
            int rem = q - ci * 100;
            int hh  = rem / 10;
            int wl  = rem - hh * 10;
            int gh  = h0 - 1 + hh;
            int gw  = w0 - 1 + wl;
            float val = 0.0f;
            if ((unsigned)gh < IMH && (unsigned)gw < IMW)
                val = xim[ci * HW + gh * IMW + gw];
            xt[ci][hh][wl] = val;
        }
        __syncthreads();

        float z[16];
#pragma unroll
        for (int i = 0; i < 16; ++i) z[i] = 0.0f;

        for (int ci = 0; ci < CIN; ++ci) {
            float nb[9];
#pragma unroll
            for (int dy = 0; dy < 3; ++dy)
#pragma unroll
                for (int dx = 0; dx < 3; ++dx)
                    nb[dy * 3 + dx] = xt[ci][ph + dy][pw + dx];
            const float* wp = cw + ci * 9;
#pragma unroll
            for (int k = 0; k < 9; ++k) {
                float xv = nb[k];
#pragma unroll
                for (int i = 0; i < 16; ++i)
                    z[i] = __builtin_fmaf(wp[(cobase + i) * (CIN * 9) + k], xv, z[i]);
            }
        }

        size_t obase = ((size_t)(t * BATCH + b) * COUT + cobase) * HW
                     + (size_t)oh * IMW + ow;
#pragma unroll
        for (int i = 0; i < 16; ++i) {
            double d  = (double)z[i] - v[i];
            double nv = v[i] + d * 0.5;
            bool  sp  = (nv >= 1.0);
            out[obase + (size_t)i * HW] = sp ? 1.0f : 0.0f;
            v[i] = sp ? 0.0 : nv;
        }
    }
}

extern "C" void kernel_launch(void* const* d_in, const int* in_sizes, int n_in,
                              void* d_out, int out_size, void* d_ws, size_t ws_size,
                              hipStream_t stream) {
    // Resolve inputs by size: x = 33.5M elems, conv_w = 36864.
    const float* x  = (const float*)d_in[0];
    const float* wf = (const float*)d_in[1];
    if (n_in >= 2) {
        if (in_sizes[0] == W_ELEMS || in_sizes[1] == X_ELEMS) {
            x  = (const float*)d_in[1];
            wf = (const float*)d_in[0];
        }
    }
    float* out = (float*)d_out;
    (void)out_size;

    if (ws_size >= (size_t)W_BYTES + 1024) {
        float* wt = (float*)d_ws;
        float* zp = (float*)((char*)d_ws + W_BYTES);   // 1KB zero pool
        hipMemsetAsync(zp, 0, 1024, stream);
        hipLaunchKernelGGL(transpose_weights, dim3((W_ELEMS + 255) / 256), dim3(256), 0, stream, wf, wt);
        hipLaunchKernelGGL(snn_conv_lif_f0, dim3(BATCH * 64), dim3(256), 0, stream, x, wt, zp, out);
    } else {
        hipLaunchKernelGGL(snn_conv_lif_f0_direct, dim3(BATCH * 64), dim3(256), 0, stream, x, wf, out);
    }
}

// Round 23
// 681.270 us; speedup vs baseline: 1.0269x; 1.0269x over previous
//
#include <hip/hip_runtime.h>

// SNN: conv2d(3x3, same, no bias, Cin=Cout=64) + LIF scan (tau=2, v_th=1, hard reset)
// Numerics contract (R13, PASS R14/R15/R20/R21/R22):
//   conv: f32, SINGLE FMA chain per output in flat (ci, ky, kx) order g=ci*9+k
//   scan: float64, v' = v + (z - v)*0.5, spike = v' >= 1.0, hard reset to 0.
// R23: kill the champion's 25-reg spill WITHOUT the LDS double-buffer price
// (R22: -spill but 2 blocks/CU -> 763us). Split c_out across blocks: grid 2048,
// each block = 32 c_out (4 waves x 8), same 25.6KB tile + r[25] async prefetch.
// Per-thread live ~60 VGPR <= 64 -> fits the proven-fast (256,4) regime clean.
// Costs: x staged 2x (+~210MB FETCH at 15% BW = cheap), LDS reads 2x (free).
// Gains: -240MB scratch traffic, occupancy 16 -> ~24 waves/CU.

#define T_STEPS 8
#define BATCH   16
#define CIN     64
#define COUT    64
#define IMH     64
#define IMW     64
#define HW      (IMH * IMW)
#define X_ELEMS (T_STEPS * BATCH * CIN * HW)   // 33,554,432
#define W_ELEMS (COUT * CIN * 9)               // 36,864

// [co][g] -> [g][co]: per (ci,k) step, a wave's 8 weights are one contiguous
// 32B block (2x float4, L2-hot).
__global__ void transpose_weights(const float* __restrict__ wf, float* __restrict__ wt) {
    int i = blockIdx.x * 256 + threadIdx.x;     // i = co*576 + g
    if (i < W_ELEMS) {
        int co = i / 576;
        int g  = i - co * 576;
        wt[g * 64 + co] = wf[i];
    }
}

__device__ __forceinline__ float stage_load(const float* xim, int h0, int w0,
                                            int q) {
    int ci  = q / 100;
    int rem = q - ci * 100;
    int hh  = rem / 10;
    int wl  = rem - hh * 10;
    int gh  = h0 - 1 + hh;
    int gw  = w0 - 1 + wl;
    float val = 0.0f;
    if ((unsigned)gh < IMH && (unsigned)gw < IMW)
        val = xim[ci * HW + gh * IMW + gw];
    return val;
}

__global__ __launch_bounds__(256, 4)
void snn_conv_lif_f0(const float* __restrict__ x, const float* __restrict__ wt,
                     float* __restrict__ out) {
    __shared__ float xt[CIN][10][10];        // linear 25.6 KB (champion layout, 25KB->25.6KB? 100/ci)

    const int tid  = threadIdx.x;
    const int lane = tid & 63;
    const int wid  = __builtin_amdgcn_readfirstlane(tid >> 6);

    const int bid  = blockIdx.x;
    const int cg   = bid & 1;                // c_out group of 32 (adjacent pair
    const int bt   = bid >> 1;               //  shares the same x tile -> L2 hit)
    const int b    = bt >> 6;                // 0..15
    const int tile = bt & 63;                // 64 tiles of 8x8
    const int h0   = (tile >> 3) << 3;
    const int w0   = (tile & 7) << 3;
    const int ph   = lane >> 3;
    const int pw   = lane & 7;
    const int cobase = (cg << 5) + (wid << 3);   // 8 c_out per wave
    const int oh = h0 + ph, ow = w0 + pw;

    double v[8];                             // f64 LIF state
#pragma unroll
    for (int i = 0; i < 8; ++i) v[i] = 0.0;

    // prefetch t=0 staging values into registers
    float r[25];
    {
        const float* xim = x + (size_t)b * CIN * HW;
#pragma unroll
        for (int j = 0; j < 25; ++j)
            r[j] = stage_load(xim, h0, w0, tid + j * 256);
    }

    for (int t = 0; t < T_STEPS; ++t) {
        __syncthreads();                     // prior compute done reading xt
        // ---- write staged regs to LDS ----
#pragma unroll
        for (int j = 0; j < 25; ++j) {
            int q   = tid + j * 256;         // 0..6399
            int ci  = q / 100;
            int rem = q - ci * 100;
            int hh  = rem / 10;
            int wl  = rem - hh * 10;
            xt[ci][hh][wl] = r[j];
        }
        __syncthreads();

        // ---- issue t+1 prefetch; HBM latency hides under the conv below ----
        if (t + 1 < T_STEPS) {
            const float* xim = x + (size_t)((t + 1) * BATCH + b) * CIN * HW;
#pragma unroll
            for (int j = 0; j < 25; ++j)
                r[j] = stage_load(xim, h0, w0, tid + j * 256);
        }

        // ---- conv: per c_out, ONE sequential FMA chain over g = ci*9+k ----
        float z[8];
#pragma unroll
        for (int i = 0; i < 8; ++i) z[i] = 0.0f;

        for (int ci = 0; ci < CIN; ++ci) {
            float nb[9];
#pragma unroll
            for (int dy = 0; dy < 3; ++dy)
#pragma unroll
                for (int dx = 0; dx < 3; ++dx)
                    nb[dy * 3 + dx] = xt[ci][ph + dy][pw + dx];

#pragma unroll
            for (int k = 0; k < 9; ++k) {
                float xv = nb[k];
                const float4* w4 = (const float4*)(wt + (ci * 9 + k) * 64 + cobase);
                float4 wa = w4[0], wb = w4[1];
                z[0] = __builtin_fmaf(wa.x, xv, z[0]);
                z[1] = __builtin_fmaf(wa.y, xv, z[1]);
                z[2] = __builtin_fmaf(wa.z, xv, z[2]);
                z[3] = __builtin_fmaf(wa.w, xv, z[3]);
                z[4] = __builtin_fmaf(wb.x, xv, z[4]);
                z[5] = __builtin_fmaf(wb.y, xv, z[5]);
                z[6] = __builtin_fmaf(wb.z, xv, z[6]);
                z[7] = __builtin_fmaf(wb.w, xv, z[7]);
            }
        }

        // ---- f64 LIF scan ----
        size_t obase = ((size_t)(t * BATCH + b) * COUT + cobase) * HW
                     + (size_t)oh * IMW + ow;
#pragma unroll
        for (int i = 0; i < 8; ++i) {
            double d  = (double)z[i] - v[i];
            double nv = v[i] + d * 0.5;
            bool  sp  = (nv >= 1.0);
            out[obase + (size_t)i * HW] = sp ? 1.0f : 0.0f;
            v[i] = sp ? 0.0 : nv;
        }
    }
}

// Fallback without workspace: identical numerics (R14-style).
__global__ __launch_bounds__(256)
void snn_conv_lif_f0_direct(const float* __restrict__ x, const float* __restrict__ cw,
                            float* __restrict__ out) {
    __shared__ float xt[CIN][10][10];

    const int tid  = threadIdx.x;
    const int lane = tid & 63;
    const int wid  = __builtin_amdgcn_readfirstlane(tid >> 6);
    const int b    = blockIdx.x >> 6;
    const int tile = blockIdx.x & 63;
    const int h0   = (tile >> 3) << 3;
    const int w0   = (tile & 7) << 3;
    const int ph   = lane >> 3, pw = lane & 7;
    const int cobase = wid << 4;
    const int oh = h0 + ph, ow = w0 + pw;

    double v[16];
#pragma unroll
    for (int i = 0; i < 16; ++i) v[i] = 0.0;

    for (int t = 0; t < T_STEPS; ++t) {
        __syncthreads();
        const float* xim = x + (size_t)(t * BATCH + b) * CIN * HW;
#pragma unroll
        for (int j = 0; j < 25; ++j) {
            int q   = tid + j * 256;
            int ci  = q / 100;
            int rem = q - ci * 100;
            int hh  = rem / 10;
            int wl  = rem - hh * 10;
            xt[ci][hh][wl] = stage_load(xim, h0, w0, q);
        }
        __syncthreads();

        float z[16];
#pragma unroll
        for (int i = 0; i < 16; ++i) z[i] = 0.0f;

        for (int ci = 0; ci < CIN; ++ci) {
            float nb[9];
#pragma unroll
            for (int dy = 0; dy < 3; ++dy)
#pragma unroll
                for (int dx = 0; dx < 3; ++dx)
                    nb[dy * 3 + dx] = xt[ci][ph + dy][pw + dx];
            const float* wp = cw + ci * 9;
#pragma unroll
            for (int k = 0; k < 9; ++k) {
                float xv = nb[k];
#pragma unroll
                for (int i = 0; i < 16; ++i)
                    z[i] = __builtin_fmaf(wp[(cobase + i) * (CIN * 9) + k], xv, z[i]);
            }
        }

        size_t obase = ((size_t)(t * BATCH + b) * COUT + cobase) * HW
                     + (size_t)oh * IMW + ow;
#pragma unroll
        for (int i = 0; i < 16; ++i) {
            double d  = (double)z[i] - v[i];
            double nv = v[i] + d * 0.5;
            bool  sp  = (nv >= 1.0);
            out[obase + (size_t)i * HW] = sp ? 1.0f : 0.0f;
            v[i] = sp ? 0.0 : nv;
        }
    }
}

extern "C" void kernel_launch(void* const* d_in, const int* in_sizes, int n_in,
                              void* d_out, int out_size, void* d_ws, size_t ws_size,
                              hipStream_t stream) {
    // Resolve inputs by size: x = 33.5M elems, conv_w = 36864.
    const float* x  = (const float*)d_in[0];
    const float* wf = (const float*)d_in[1];
    if (n_in >= 2) {
        if (in_sizes[0] == W_ELEMS || in_sizes[1] == X_ELEMS) {
            x  = (const float*)d_in[1];
            wf = (const float*)d_in[0];
        }
    }
    float* out = (float*)d_out;
    (void)out_size;

    if (ws_size >= (size_t)W_ELEMS * sizeof(float)) {
        float* wt = (float*)d_ws;
        hipLaunchKernelGGL(transpose_weights, dim3((W_ELEMS + 255) / 256), dim3(256), 0, stream, wf, wt);
        hipLaunchKernelGGL(snn_conv_lif_f0, dim3(BATCH * 64 * 2), dim3(256), 0, stream, x, wt, out);
    } else {
        hipLaunchKernelGGL(snn_conv_lif_f0_direct, dim3(BATCH * 64), dim3(256), 0, stream, x, wf, out);
    }
}

// Round 24
// 529.398 us; speedup vs baseline: 1.3215x; 1.2869x over previous
//
#include <hip/hip_runtime.h>

// SNN: conv2d(3x3, same, no bias, Cin=Cout=64) + LIF scan (tau=2, v_th=1, hard reset)
// Numerics contract (R13 discriminators, bit-exact PASS R14/R15/R20):
//   conv: f32, SINGLE FMA chain per output in flat (ci, ky, kx) order g=ci*9+k
//   scan: float64, v' = v + (z - v)*0.5, spike = v' >= 1.0, hard reset to 0.
// FINAL (R24) = exact champion (R15/R20, 527us bench / 592us steady):
//   - 1024 blocks x 256 thr; 8x8 pixel tile/wave; 16 c_out/wave
//   - LDS halo tile stride-12 (read aliasing 2-way max = free)
//   - T14 async-STAGE: t+1's 25 loads into regs, hidden under conv
//   - float4 weight loads from d_ws-transposed [g][co] (L2-hot)
//   - __launch_bounds__(256,4): the empirically-fast compile regime; its
//     ~25-reg spill (+240MB scratch) is cheaper than every alternative tried
//     (R16-R19 scalarized-SMEM 2.2ms; R21/R22/R23 625-763us).

#define T_STEPS 8
#define BATCH   16
#define CIN     64
#define COUT    64
#define IMH     64
#define IMW     64
#define HW      (IMH * IMW)
#define X_ELEMS (T_STEPS * BATCH * CIN * HW)   // 33,554,432
#define W_ELEMS (COUT * CIN * 9)               // 36,864

__global__ void transpose_weights(const float* __restrict__ wf, float* __restrict__ wt) {
    int i = blockIdx.x * 256 + threadIdx.x;     // i = co*576 + g
    if (i < W_ELEMS) {
        int co = i / 576;
        int g  = i - co * 576;
        wt[g * 64 + co] = wf[i];
    }
}

__device__ __forceinline__ float stage_load(const float* xim, int h0, int w0,
                                            int q) {
    int ci  = q / 100;
    int rem = q - ci * 100;
    int hh  = rem / 10;
    int wl  = rem - hh * 10;
    int gh  = h0 - 1 + hh;
    int gw  = w0 - 1 + wl;
    float val = 0.0f;
    if ((unsigned)gh < IMH && (unsigned)gw < IMW)
        val = xim[ci * HW + gh * IMW + gw];
    return val;
}

__global__ __launch_bounds__(256, 4)
void snn_conv_lif_f0(const float* __restrict__ x, const float* __restrict__ wt,
                     float* __restrict__ out) {
    __shared__ float xt[CIN][10][12];   // padded stride 12: 30.7 KB

    const int tid  = threadIdx.x;
    const int lane = tid & 63;
    const int wid  = __builtin_amdgcn_readfirstlane(tid >> 6);

    const int b    = blockIdx.x >> 6;        // 0..15
    const int tile = blockIdx.x & 63;        // 64 tiles of 8x8
    const int h0   = (tile >> 3) << 3;
    const int w0   = (tile & 7) << 3;
    const int ph   = lane >> 3;
    const int pw   = lane & 7;
    const int cobase = wid << 4;             // 16 c_out per wave
    const int oh = h0 + ph, ow = w0 + pw;

    double v[16];                            // f64 LIF state
#pragma unroll
    for (int i = 0; i < 16; ++i) v[i] = 0.0;

    // prefetch t=0 staging values into registers
    float r[25];
    {
        const float* xim = x + (size_t)b * CIN * HW;
#pragma unroll
        for (int j = 0; j < 25; ++j)
            r[j] = stage_load(xim, h0, w0, tid + j * 256);
    }

    for (int t = 0; t < T_STEPS; ++t) {
        __syncthreads();                     // prior compute done reading xt
        // ---- write staged regs to (padded) LDS ----
#pragma unroll
        for (int j = 0; j < 25; ++j) {
            int q   = tid + j * 256;         // 0..6399
            int ci  = q / 100;
            int rem = q - ci * 100;
            int hh  = rem / 10;
            int wl  = rem - hh * 10;
            xt[ci][hh][wl] = r[j];
        }
        __syncthreads();

        // ---- issue t+1 prefetch; HBM latency hides under the conv below ----
        if (t + 1 < T_STEPS) {
            const float* xim = x + (size_t)((t + 1) * BATCH + b) * CIN * HW;
#pragma unroll
            for (int j = 0; j < 25; ++j)
                r[j] = stage_load(xim, h0, w0, tid + j * 256);
        }

        // ---- conv: per c_out, ONE sequential FMA chain over g = ci*9+k ----
        float z[16];
#pragma unroll
        for (int i = 0; i < 16; ++i) z[i] = 0.0f;

        for (int ci = 0; ci < CIN; ++ci) {
            float nb[9];
#pragma unroll
            for (int dy = 0; dy < 3; ++dy)
#pragma unroll
                for (int dx = 0; dx < 3; ++dx)
                    nb[dy * 3 + dx] = xt[ci][ph + dy][pw + dx];

#pragma unroll
            for (int k = 0; k < 9; ++k) {
                float xv = nb[k];
                const float4* w4 = (const float4*)(wt + (ci * 9 + k) * 64 + cobase);
                float4 wa = w4[0], wb = w4[1], wc = w4[2], wd = w4[3];
                z[0]  = __builtin_fmaf(wa.x, xv, z[0]);
                z[1]  = __builtin_fmaf(wa.y, xv, z[1]);
                z[2]  = __builtin_fmaf(wa.z, xv, z[2]);
                z[3]  = __builtin_fmaf(wa.w, xv, z[3]);
                z[4]  = __builtin_fmaf(wb.x, xv, z[4]);
                z[5]  = __builtin_fmaf(wb.y, xv, z[5]);
                z[6]  = __builtin_fmaf(wb.z, xv, z[6]);
                z[7]  = __builtin_fmaf(wb.w, xv, z[7]);
                z[8]  = __builtin_fmaf(wc.x, xv, z[8]);
                z[9]  = __builtin_fmaf(wc.y, xv, z[9]);
                z[10] = __builtin_fmaf(wc.z, xv, z[10]);
                z[11] = __builtin_fmaf(wc.w, xv, z[11]);
                z[12] = __builtin_fmaf(wd.x, xv, z[12]);
                z[13] = __builtin_fmaf(wd.y, xv, z[13]);
                z[14] = __builtin_fmaf(wd.z, xv, z[14]);
                z[15] = __builtin_fmaf(wd.w, xv, z[15]);
            }
        }

        // ---- f64 LIF scan ----
        size_t obase = ((size_t)(t * BATCH + b) * COUT + cobase) * HW
                     + (size_t)oh * IMW + ow;
#pragma unroll
        for (int i = 0; i < 16; ++i) {
            double d  = (double)z[i] - v[i];
            double nv = v[i] + d * 0.5;
            bool  sp  = (nv >= 1.0);
            out[obase + (size_t)i * HW] = sp ? 1.0f : 0.0f;
            v[i] = sp ? 0.0 : nv;
        }
    }
}

// Fallback without workspace: identical numerics, strided weight reads.
__global__ __launch_bounds__(256)
void snn_conv_lif_f0_direct(const float* __restrict__ x, const float* __restrict__ cw,
                            float* __restrict__ out) {
    __shared__ float xt[CIN][10][12];

    const int tid  = threadIdx.x;
    const int lane = tid & 63;
    const int wid  = __builtin_amdgcn_readfirstlane(tid >> 6);
    const int b    = blockIdx.x >> 6;
    const int tile = blockIdx.x & 63;
    const int h0   = (tile >> 3) << 3;
    const int w0   = (tile & 7) << 3;
    const int ph   = lane >> 3, pw = lane & 7;
    const int cobase = wid << 4;
    const int oh = h0 + ph, ow = w0 + pw;

    double v[16];
#pragma unroll
    for (int i = 0; i < 16; ++i) v[i] = 0.0;

    for (int t = 0; t < T_STEPS; ++t) {
        __syncthreads();
        const float* xim = x + (size_t)(t * BATCH + b) * CIN * HW;
#pragma unroll
        for (int j = 0; j < 25; ++j) {
            int q   = tid + j * 256;
            int ci  = q / 100;
            int rem = q - ci * 100;
            int hh  = rem / 10;
            int wl  = rem - hh * 10;
            xt[ci][hh][wl] = stage_load(xim, h0, w0, q);
        }
        __syncthreads();

        float z[16];
#pragma unroll
        for (int i = 0; i < 16; ++i) z[i] = 0.0f;

        for (int ci = 0; ci < CIN; ++ci) {
            float nb[9];
#pragma unroll
            for (int dy = 0; dy < 3; ++dy)
#pragma unroll
                for (int dx = 0; dx < 3; ++dx)
                    nb[dy * 3 + dx] = xt[ci][ph + dy][pw + dx];
            const float* wp = cw + ci * 9;
#pragma unroll
            for (int k = 0; k < 9; ++k) {
                float xv = nb[k];
#pragma unroll
                for (int i = 0; i < 16; ++i)
                    z[i] = __builtin_fmaf(wp[(cobase + i) * (CIN * 9) + k], xv, z[i]);
            }
        }

        size_t obase = ((size_t)(t * BATCH + b) * COUT + cobase) * HW
                     + (size_t)oh * IMW + ow;
#pragma unroll
        for (int i = 0; i < 16; ++i) {
            double d  = (double)z[i] - v[i];
            double nv = v[i] + d * 0.5;
            bool  sp  = (nv >= 1.0);
            out[obase + (size_t)i * HW] = sp ? 1.0f : 0.0f;
            v[i] = sp ? 0.0 : nv;
        }
    }
}

extern "C" void kernel_launch(void* const* d_in, const int* in_sizes, int n_in,
                              void* d_out, int out_size, void* d_ws, size_t ws_size,
                              hipStream_t stream) {
    // Resolve inputs by size: x = 33.5M elems, conv_w = 36864.
    const float* x  = (const float*)d_in[0];
    const float* wf = (const float*)d_in[1];
    if (n_in >= 2) {
        if (in_sizes[0] == W_ELEMS || in_sizes[1] == X_ELEMS) {
            x  = (const float*)d_in[1];
            wf = (const float*)d_in[0];
        }
    }
    float* out = (float*)d_out;
    (void)out_size;

    dim3 grid(BATCH * 64);
    dim3 block(256);

    if (ws_size >= (size_t)W_ELEMS * sizeof(float)) {
        float* wt = (float*)d_ws;
        hipLaunchKernelGGL(transpose_weights, dim3((W_ELEMS + 255) / 256), block, 0, stream, wf, wt);
        hipLaunchKernelGGL(snn_conv_lif_f0, grid, block, 0, stream, x, wt, out);
    } else {
        hipLaunchKernelGGL(snn_conv_lif_f0_direct, grid, block, 0, stream, x, wf, out);
    }
}

// Round 25
// 527.078 us; speedup vs baseline: 1.3273x; 1.0044x over previous
//
#include <hip/hip_runtime.h>

// SNN: conv2d(3x3, same, no bias, Cin=Cout=64) + LIF scan (tau=2, v_th=1, hard reset)
// Numerics contract (R13 discriminators, bit-exact PASS R14/R15/R20/R24):
//   conv: f32, SINGLE FMA chain per output in flat (ci, ky, kx) order g=ci*9+k
//   scan: float64, v' = v + (z - v)*0.5, spike = v' >= 1.0, hard reset to 0.
// TERMINAL KERNEL (= champion R15/R20/R24, 527-529us bench, 3x reproduced):
//   - 1024 blocks x 256 thr; 8x8 pixel tile/wave; 16 c_out/wave
//   - LDS halo tile stride-12 (read aliasing 2-way max = free)
//   - T14 async-STAGE: t+1's 25 loads into regs, hidden under conv
//   - float4 weight loads from d_ws-transposed [g][co] (L2-hot)
//   - __launch_bounds__(256,4): the empirically-fast compile regime; its
//     ~25-reg spill (+240MB scratch) is cheaper than every alternative tried
//     (R16-R19 scalarized-SMEM 2.2ms; R21/R22/R23 625-763us).

#define T_STEPS 8
#define BATCH   16
#define CIN     64
#define COUT    64
#define IMH     64
#define IMW     64
#define HW      (IMH * IMW)
#define X_ELEMS (T_STEPS * BATCH * CIN * HW)   // 33,554,432
#define W_ELEMS (COUT * CIN * 9)               // 36,864

__global__ void transpose_weights(const float* __restrict__ wf, float* __restrict__ wt) {
    int i = blockIdx.x * 256 + threadIdx.x;     // i = co*576 + g
    if (i < W_ELEMS) {
        int co = i / 576;
        int g  = i - co * 576;
        wt[g * 64 + co] = wf[i];
    }
}

__device__ __forceinline__ float stage_load(const float* xim, int h0, int w0,
                                            int q) {
    int ci  = q / 100;
    int rem = q - ci * 100;
    int hh  = rem / 10;
    int wl  = rem - hh * 10;
    int gh  = h0 - 1 + hh;
    int gw  = w0 - 1 + wl;
    float val = 0.0f;
    if ((unsigned)gh < IMH && (unsigned)gw < IMW)
        val = xim[ci * HW + gh * IMW + gw];
    return val;
}

__global__ __launch_bounds__(256, 4)
void snn_conv_lif_f0(const float* __restrict__ x, const float* __restrict__ wt,
                     float* __restrict__ out) {
    __shared__ float xt[CIN][10][12];   // padded stride 12: 30.7 KB

    const int tid  = threadIdx.x;
    const int lane = tid & 63;
    const int wid  = __builtin_amdgcn_readfirstlane(tid >> 6);

    const int b    = blockIdx.x >> 6;        // 0..15
    const int tile = blockIdx.x & 63;        // 64 tiles of 8x8
    const int h0   = (tile >> 3) << 3;
    const int w0   = (tile & 7) << 3;
    const int ph   = lane >> 3;
    const int pw   = lane & 7;
    const int cobase = wid << 4;             // 16 c_out per wave
    const int oh = h0 + ph, ow = w0 + pw;

    double v[16];                            // f64 LIF state
#pragma unroll
    for (int i = 0; i < 16; ++i) v[i] = 0.0;

    // prefetch t=0 staging values into registers
    float r[25];
    {
        const float* xim = x + (size_t)b * CIN * HW;
#pragma unroll
        for (int j = 0; j < 25; ++j)
            r[j] = stage_load(xim, h0, w0, tid + j * 256);
    }

    for (int t = 0; t < T_STEPS; ++t) {
        __syncthreads();                     // prior compute done reading xt
        // ---- write staged regs to (padded) LDS ----
#pragma unroll
        for (int j = 0; j < 25; ++j) {
            int q   = tid + j * 256;         // 0..6399
            int ci  = q / 100;
            int rem = q - ci * 100;
            int hh  = rem / 10;
            int wl  = rem - hh * 10;
            xt[ci][hh][wl] = r[j];
        }
        __syncthreads();

        // ---- issue t+1 prefetch; HBM latency hides under the conv below ----
        if (t + 1 < T_STEPS) {
            const float* xim = x + (size_t)((t + 1) * BATCH + b) * CIN * HW;
#pragma unroll
            for (int j = 0; j < 25; ++j)
                r[j] = stage_load(xim, h0, w0, tid + j * 256);
        }

        // ---- conv: per c_out, ONE sequential FMA chain over g = ci*9+k ----
        float z[16];
#pragma unroll
        for (int i = 0; i < 16; ++i) z[i] = 0.0f;

        for (int ci = 0; ci < CIN; ++ci) {
            float nb[9];
#pragma unroll
            for (int dy = 0; dy < 3; ++dy)
#pragma unroll
                for (int dx = 0; dx < 3; ++dx)
                    nb[dy * 3 + dx] = xt[ci][ph + dy][pw + dx];

#pragma unroll
            for (int k = 0; k < 9; ++k) {
                float xv = nb[k];
                const float4* w4 = (const float4*)(wt + (ci * 9 + k) * 64 + cobase);
                float4 wa = w4[0], wb = w4[1], wc = w4[2], wd = w4[3];
                z[0]  = __builtin_fmaf(wa.x, xv, z[0]);
                z[1]  = __builtin_fmaf(wa.y, xv, z[1]);
                z[2]  = __builtin_fmaf(wa.z, xv, z[2]);
                z[3]  = __builtin_fmaf(wa.w, xv, z[3]);
                z[4]  = __builtin_fmaf(wb.x, xv, z[4]);
                z[5]  = __builtin_fmaf(wb.y, xv, z[5]);
                z[6]  = __builtin_fmaf(wb.z, xv, z[6]);
                z[7]  = __builtin_fmaf(wb.w, xv, z[7]);
                z[8]  = __builtin_fmaf(wc.x, xv, z[8]);
                z[9]  = __builtin_fmaf(wc.y, xv, z[9]);
                z[10] = __builtin_fmaf(wc.z, xv, z[10]);
                z[11] = __builtin_fmaf(wc.w, xv, z[11]);
                z[12] = __builtin_fmaf(wd.x, xv, z[12]);
                z[13] = __builtin_fmaf(wd.y, xv, z[13]);
                z[14] = __builtin_fmaf(wd.z, xv, z[14]);
                z[15] = __builtin_fmaf(wd.w, xv, z[15]);
            }
        }

        // ---- f64 LIF scan ----
        size_t obase = ((size_t)(t * BATCH + b) * COUT + cobase) * HW
                     + (size_t)oh * IMW + ow;
#pragma unroll
        for (int i = 0; i < 16; ++i) {
            double d  = (double)z[i] - v[i];
            double nv = v[i] + d * 0.5;
            bool  sp  = (nv >= 1.0);
            out[obase + (size_t)i * HW] = sp ? 1.0f : 0.0f;
            v[i] = sp ? 0.0 : nv;
        }
    }
}

// Fallback without workspace: identical numerics, strided weight reads.
__global__ __launch_bounds__(256)
void snn_conv_lif_f0_direct(const float* __restrict__ x, const float* __restrict__ cw,
                            float* __restrict__ out) {
    __shared__ float xt[CIN][10][12];

    const int tid  = threadIdx.x;
    const int lane = tid & 63;
    const int wid  = __builtin_amdgcn_readfirstlane(tid >> 6);
    const int b    = blockIdx.x >> 6;
    const int tile = blockIdx.x & 63;
    const int h0   = (tile >> 3) << 3;
    const int w0   = (tile & 7) << 3;
    const int ph   = lane >> 3, pw = lane & 7;
    const int cobase = wid << 4;
    const int oh = h0 + ph, ow = w0 + pw;

    double v[16];
#pragma unroll
    for (int i = 0; i < 16; ++i) v[i] = 0.0;

    for (int t = 0; t < T_STEPS; ++t) {
        __syncthreads();
        const float* xim = x + (size_t)(t * BATCH + b) * CIN * HW;
#pragma unroll
        for (int j = 0; j < 25; ++j) {
            int q   = tid + j * 256;
            int ci  = q / 100;
            int rem = q - ci * 100;
            int hh  = rem / 10;
            int wl  = rem - hh * 10;
            xt[ci][hh][wl] = stage_load(xim, h0, w0, q);
        }
        __syncthreads();

        float z[16];
#pragma unroll
        for (int i = 0; i < 16; ++i) z[i] = 0.0f;

        for (int ci = 0; ci < CIN; ++ci) {
            float nb[9];
#pragma unroll
            for (int dy = 0; dy < 3; ++dy)
#pragma unroll
                for (int dx = 0; dx < 3; ++dx)
                    nb[dy * 3 + dx] = xt[ci][ph + dy][pw + dx];
            const float* wp = cw + ci * 9;
#pragma unroll
            for (int k = 0; k < 9; ++k) {
                float xv = nb[k];
#pragma unroll
                for (int i = 0; i < 16; ++i)
                    z[i] = __builtin_fmaf(wp[(cobase + i) * (CIN * 9) + k], xv, z[i]);
            }
        }

        size_t obase = ((size_t)(t * BATCH + b) * COUT + cobase) * HW
                     + (size_t)oh * IMW + ow;
#pragma unroll
        for (int i = 0; i < 16; ++i) {
            double d  = (double)z[i] - v[i];
            double nv = v[i] + d * 0.5;
            bool  sp  = (nv >= 1.0);
            out[obase + (size_t)i * HW] = sp ? 1.0f : 0.0f;
            v[i] = sp ? 0.0 : nv;
        }
    }
}

extern "C" void kernel_launch(void* const* d_in, const int* in_sizes, int n_in,
                              void* d_out, int out_size, void* d_ws, size_t ws_size,
                              hipStream_t stream) {
    // Resolve inputs by size: x = 33.5M elems, conv_w = 36864.
    const float* x  = (const float*)d_in[0];
    const float* wf = (const float*)d_in[1];
    if (n_in >= 2) {
        if (in_sizes[0] == W_ELEMS || in_sizes[1] == X_ELEMS) {
            x  = (const float*)d_in[1];
            wf = (const float*)d_in[0];
        }
    }
    float* out = (float*)d_out;
    (void)out_size;

    dim3 grid(BATCH * 64);
    dim3 block(256);

    if (ws_size >= (size_t)W_ELEMS * sizeof(float)) {
        float* wt = (float*)d_ws;
        hipLaunchKernelGGL(transpose_weights, dim3((W_ELEMS + 255) / 256), block, 0, stream, wf, wt);
        hipLaunchKernelGGL(snn_conv_lif_f0, grid, block, 0, stream, x, wt, out);
    } else {
        hipLaunchKernelGGL(snn_conv_lif_f0_direct, grid, block, 0, stream, x, wf, out);
    }
}